// Round 2
// baseline (17796.875 us; speedup 1.0000x reference)
//
#include <hip/hip_runtime.h>
#include <math.h>

#define WW 256
#define HH 256
#define DDP 96
#define HWP (WW*HH)            // 65536
#define DHW (DDP*HWP)          // 6291456 per volume
#define N2 (2*DHW)             // one tensor (B=2,C=1)
#define TX 32
#define TY 8
#define NTHREADS 256
#define RED_BLOCKS 1024
#define NITER 40

__device__ __forceinline__ float fmin3(float a, float b, float c) { return fminf(a, fminf(b, c)); }
__device__ __forceinline__ float fmax3(float a, float b, float c) { return fmaxf(a, fmaxf(b, c)); }
__device__ __forceinline__ float sigm(float x) { return 1.f / (1.f + expf(-x)); }

// ---------------- 3x3x3 min-pool (erosion), SAME-clamped, rolling z-sweep ----------------
// APPLY_SIG: apply sigmoid to the pooled value at write (valid since sigmoid is monotone:
// sigmoid(min window) == min window of sigmoid).
template<bool APPLY_SIG>
__global__ __launch_bounds__(NTHREADS) void erode_kernel(const float* __restrict__ in,
                                                         float* __restrict__ out) {
    const int lx = threadIdx.x & (TX - 1);
    const int ly = threadIdx.x >> 5;
    const int x0 = blockIdx.x * TX;
    const int y0 = blockIdx.y * TY;
    const size_t base = (size_t)blockIdx.z * DHW;

    __shared__ float raw[TY + 2][TX + 2];
    __shared__ float mx1[TY + 2][TX];

    const float G = INFINITY;
    float r0 = G, r1 = G, r2 = G;

    for (int zi = 0; zi <= DDP; ++zi) {
        float a = G;
        if (zi < DDP) {
            const float* pl = in + base + (size_t)zi * HWP;
            for (int i = threadIdx.x; i < (TY + 2) * (TX + 2); i += NTHREADS) {
                int ry = i / (TX + 2);
                int rx = i - ry * (TX + 2);
                int gy = y0 + ry - 1;
                int gx = x0 + rx - 1;
                float v = G;
                if ((unsigned)gy < HH && (unsigned)gx < WW) v = pl[gy * WW + gx];
                raw[ry][rx] = v;
            }
            __syncthreads();
            for (int i = threadIdx.x; i < (TY + 2) * TX; i += NTHREADS) {
                int ry = i >> 5;
                int rx = i & (TX - 1);
                mx1[ry][rx] = fmin3(raw[ry][rx], raw[ry][rx + 1], raw[ry][rx + 2]);
            }
            __syncthreads();
            a = fmin3(mx1[ly][lx], mx1[ly + 1][lx], mx1[ly + 2][lx]);
        }
        r0 = r1; r1 = r2; r2 = a;
        if (zi >= 1) {
            int zc = zi - 1;
            float v = fmin3(r0, r1, r2);
            if (APPLY_SIG) v = sigm(v);
            out[base + (size_t)zc * HWP + (size_t)((y0 + ly) * WW + x0 + lx)] = v;
        }
        __syncthreads();
    }
}

// ---------------- 3x3x3 max-pool of e, fused with skel update ----------------
// INIT:  skel = relu(aimg - M(e))          (SIG_A: aimg passed through sigmoid)
// else:  delta = relu(aimg - M(e)); skel += relu(delta - skel*delta)
template<bool INIT, bool SIG_A>
__global__ __launch_bounds__(NTHREADS) void maxupd_kernel(const float* __restrict__ e,
                                                          const float* __restrict__ aimg,
                                                          float* __restrict__ skel) {
    const int lx = threadIdx.x & (TX - 1);
    const int ly = threadIdx.x >> 5;
    const int x0 = blockIdx.x * TX;
    const int y0 = blockIdx.y * TY;
    const size_t base = (size_t)blockIdx.z * DHW;

    __shared__ float raw[TY + 2][TX + 2];
    __shared__ float mx1[TY + 2][TX];

    const float G = -INFINITY;
    float r0 = G, r1 = G, r2 = G;

    for (int zi = 0; zi <= DDP; ++zi) {
        float a = G;
        if (zi < DDP) {
            const float* pl = e + base + (size_t)zi * HWP;
            for (int i = threadIdx.x; i < (TY + 2) * (TX + 2); i += NTHREADS) {
                int ry = i / (TX + 2);
                int rx = i - ry * (TX + 2);
                int gy = y0 + ry - 1;
                int gx = x0 + rx - 1;
                float v = G;
                if ((unsigned)gy < HH && (unsigned)gx < WW) v = pl[gy * WW + gx];
                raw[ry][rx] = v;
            }
            __syncthreads();
            for (int i = threadIdx.x; i < (TY + 2) * TX; i += NTHREADS) {
                int ry = i >> 5;
                int rx = i & (TX - 1);
                mx1[ry][rx] = fmax3(raw[ry][rx], raw[ry][rx + 1], raw[ry][rx + 2]);
            }
            __syncthreads();
            a = fmax3(mx1[ly][lx], mx1[ly + 1][lx], mx1[ly + 2][lx]);
        }
        r0 = r1; r1 = r2; r2 = a;
        if (zi >= 1) {
            int zc = zi - 1;
            size_t idx = base + (size_t)zc * HWP + (size_t)((y0 + ly) * WW + x0 + lx);
            float o = fmax3(r0, r1, r2);
            float av = aimg[idx];
            if (SIG_A) av = sigm(av);
            float d = fmaxf(av - o, 0.f);
            if (INIT) {
                skel[idx] = d;
            } else {
                float s = skel[idx];
                skel[idx] = s + fmaxf(d - s * d, 0.f);
            }
        }
        __syncthreads();
    }
}

// ---------------- deterministic 2-sum reduction: p0 += sum(skel*f(other)), p1 += sum(skel) ----
template<bool SIG_O, bool ACCUM>
__global__ __launch_bounds__(NTHREADS) void reduce2_kernel(const float* __restrict__ skel,
                                                           const float* __restrict__ other,
                                                           float* __restrict__ p0,
                                                           float* __restrict__ p1,
                                                           int n) {
    float a0 = 0.f, a1 = 0.f;
    for (int i = blockIdx.x * NTHREADS + threadIdx.x; i < n; i += gridDim.x * NTHREADS) {
        float s = skel[i];
        float o = other[i];
        if (SIG_O) o = sigm(o);
        a0 += s * o;
        a1 += s;
    }
    for (int off = 32; off > 0; off >>= 1) {
        a0 += __shfl_down(a0, off);
        a1 += __shfl_down(a1, off);
    }
    __shared__ float red[4][2];
    int wave = threadIdx.x >> 6;
    if ((threadIdx.x & 63) == 0) { red[wave][0] = a0; red[wave][1] = a1; }
    __syncthreads();
    if (threadIdx.x == 0) {
        float s0 = 0.f, s1 = 0.f;
        for (int w = 0; w < 4; ++w) { s0 += red[w][0]; s1 += red[w][1]; }
        if (ACCUM) { p0[blockIdx.x] += s0; p1[blockIdx.x] += s1; }
        else       { p0[blockIdx.x] = s0;  p1[blockIdx.x] = s1;  }
    }
}

__global__ __launch_bounds__(NTHREADS) void finalize_kernel(const float* __restrict__ part,
                                                            float* __restrict__ out) {
    float a0 = 0.f, a1 = 0.f, a2 = 0.f, a3 = 0.f;
    for (int i = threadIdx.x; i < RED_BLOCKS; i += NTHREADS) {
        a0 += part[0 * RED_BLOCKS + i];
        a1 += part[1 * RED_BLOCKS + i];
        a2 += part[2 * RED_BLOCKS + i];
        a3 += part[3 * RED_BLOCKS + i];
    }
    for (int off = 32; off > 0; off >>= 1) {
        a0 += __shfl_down(a0, off);
        a1 += __shfl_down(a1, off);
        a2 += __shfl_down(a2, off);
        a3 += __shfl_down(a3, off);
    }
    __shared__ float red[4][4];
    int wave = threadIdx.x >> 6;
    if ((threadIdx.x & 63) == 0) {
        red[wave][0] = a0; red[wave][1] = a1; red[wave][2] = a2; red[wave][3] = a3;
    }
    __syncthreads();
    if (threadIdx.x == 0) {
        float s0 = 0.f, s1 = 0.f, s2 = 0.f, s3 = 0.f;
        for (int w = 0; w < 4; ++w) {
            s0 += red[w][0]; s1 += red[w][1]; s2 += red[w][2]; s3 += red[w][3];
        }
        float tprec = (s0 + 1.f) / (s1 + 1.f);
        float tsens = (s2 + 1.f) / (s3 + 1.f);
        float cl = 2.f * tprec * tsens / (tprec + tsens + 1.f);
        out[0] = 1.f - cl;
    }
}

__global__ void sentinel_kernel(float* out, float v) { out[0] = v; }

// Run one branch's skeletonization chain on `vols` volumes starting at `input`.
// A,B,SKEL are ws buffers of vols*DHW elements each.
static void run_branch(const float* input, bool dosig,
                       float* A, float* B, float* SKEL,
                       int vols, hipStream_t stream) {
    dim3 grid(WW / TX, HH / TY, vols);
    // e1 = E(img0) (sigmoid fused for pred branch)
    if (dosig) erode_kernel<true ><<<grid, NTHREADS, 0, stream>>>(input, B);
    else       erode_kernel<false><<<grid, NTHREADS, 0, stream>>>(input, B);
    // skel = relu(img0 - M(e1))
    if (dosig) maxupd_kernel<true, true ><<<grid, NTHREADS, 0, stream>>>(B, input, SKEL);
    else       maxupd_kernel<true, false><<<grid, NTHREADS, 0, stream>>>(B, input, SKEL);
    float* cur = B;
    float* oth = A;
    for (int t = 0; t < NITER; ++t) {
        erode_kernel<false><<<grid, NTHREADS, 0, stream>>>(cur, oth);            // e_{t+2}
        maxupd_kernel<false, false><<<grid, NTHREADS, 0, stream>>>(oth, cur, SKEL);
        float* tmp = cur; cur = oth; oth = tmp;
    }
}

extern "C" void kernel_launch(void* const* d_in, const int* in_sizes, int n_in,
                              void* d_out, int out_size, void* d_ws, size_t ws_size,
                              hipStream_t stream) {
    const float* ypred = (const float*)d_in[0];
    const float* ytrue = (const float*)d_in[1];
    float* out = (float*)d_out;

    const size_t partBytes = (size_t)4 * RED_BLOCKS * sizeof(float);
    const size_t need2 = (size_t)3 * N2 * sizeof(float) + partBytes;   // ~151 MB
    const size_t need1 = (size_t)3 * DHW * sizeof(float) + partBytes;  // ~75.5 MB

    if (ws_size >= need2) {
        // -------- per-branch mode (2 volumes per pass) --------
        float* A    = (float*)d_ws;
        float* B    = A + N2;
        float* SKEL = B + N2;
        float* PART = SKEL + N2;

        // pred branch
        run_branch(ypred, true, A, B, SKEL, 2, stream);
        reduce2_kernel<false, false><<<RED_BLOCKS, NTHREADS, 0, stream>>>(
            SKEL, ytrue, PART + 0 * RED_BLOCKS, PART + 1 * RED_BLOCKS, N2);
        // true branch
        run_branch(ytrue, false, A, B, SKEL, 2, stream);
        reduce2_kernel<true, false><<<RED_BLOCKS, NTHREADS, 0, stream>>>(
            SKEL, ypred, PART + 2 * RED_BLOCKS, PART + 3 * RED_BLOCKS, N2);

        finalize_kernel<<<1, NTHREADS, 0, stream>>>(PART, out);
    } else if (ws_size >= need1) {
        // -------- per-volume mode (1 volume per pass) --------
        float* A    = (float*)d_ws;
        float* B    = A + DHW;
        float* SKEL = B + DHW;
        float* PART = SKEL + DHW;

        for (int v = 0; v < 2; ++v) {
            run_branch(ypred + (size_t)v * DHW, true, A, B, SKEL, 1, stream);
            if (v == 0)
                reduce2_kernel<false, false><<<RED_BLOCKS, NTHREADS, 0, stream>>>(
                    SKEL, ytrue + (size_t)v * DHW, PART + 0 * RED_BLOCKS, PART + 1 * RED_BLOCKS, DHW);
            else
                reduce2_kernel<false, true><<<RED_BLOCKS, NTHREADS, 0, stream>>>(
                    SKEL, ytrue + (size_t)v * DHW, PART + 0 * RED_BLOCKS, PART + 1 * RED_BLOCKS, DHW);
        }
        for (int v = 0; v < 2; ++v) {
            run_branch(ytrue + (size_t)v * DHW, false, A, B, SKEL, 1, stream);
            if (v == 0)
                reduce2_kernel<true, false><<<RED_BLOCKS, NTHREADS, 0, stream>>>(
                    SKEL, ypred + (size_t)v * DHW, PART + 2 * RED_BLOCKS, PART + 3 * RED_BLOCKS, DHW);
            else
                reduce2_kernel<true, true><<<RED_BLOCKS, NTHREADS, 0, stream>>>(
                    SKEL, ypred + (size_t)v * DHW, PART + 2 * RED_BLOCKS, PART + 3 * RED_BLOCKS, DHW);
        }
        finalize_kernel<<<1, NTHREADS, 0, stream>>>(PART, out);
    } else {
        sentinel_kernel<<<1, 1, 0, stream>>>(out, -111111.f);
    }
}

// Round 3
// 6829.914 us; speedup vs baseline: 2.6057x; 2.6057x over previous
//
#include <hip/hip_runtime.h>
#include <math.h>

#define WW 256
#define HH 256
#define DDP 96
#define HWP (WW*HH)            // 65536
#define DHW (DDP*HWP)          // 6291456 per volume
#define N2 (2*DHW)             // one tensor (B=2,C=1)
#define TX 32
#define TY 8
#define NTHREADS 256
#define RED_BLOCKS 1024
#define NITER 40
#define ZS 12                  // z-slab depth
#define NSLAB (DDP/ZS)         // 8 slabs per volume

__device__ __forceinline__ float fmin3(float a, float b, float c) { return fminf(a, fminf(b, c)); }
__device__ __forceinline__ float fmax3(float a, float b, float c) { return fmaxf(a, fmaxf(b, c)); }
__device__ __forceinline__ float sigm(float x) { return 1.f / (1.f + expf(-x)); }

// ---------------- 3x3x3 min-pool (erosion), SAME-clamped, z-slab rolling sweep ----------------
template<bool APPLY_SIG>
__global__ __launch_bounds__(NTHREADS) void erode_kernel(const float* __restrict__ in,
                                                         float* __restrict__ out) {
    const int lx = threadIdx.x & (TX - 1);
    const int ly = threadIdx.x >> 5;
    const int x0 = blockIdx.x * TX;
    const int y0 = blockIdx.y * TY;
    const int slab = blockIdx.z % NSLAB;
    const int z0 = slab * ZS;
    const size_t base = (size_t)(blockIdx.z / NSLAB) * DHW;

    __shared__ float raw[TY + 2][TX + 2];
    __shared__ float mx1[TY + 2][TX];

    const float G = INFINITY;
    float r1 = G, r2 = G;

    for (int zi = z0 - 1; zi <= z0 + ZS; ++zi) {   // ZS+2 steps
        float a = G;
        if ((unsigned)zi < DDP) {
            const float* pl = in + base + (size_t)zi * HWP;
            for (int i = threadIdx.x; i < (TY + 2) * (TX + 2); i += NTHREADS) {
                int ry = i / (TX + 2);
                int rx = i - ry * (TX + 2);
                int gy = y0 + ry - 1;
                int gx = x0 + rx - 1;
                float v = G;
                if ((unsigned)gy < HH && (unsigned)gx < WW) v = pl[gy * WW + gx];
                raw[ry][rx] = v;
            }
            __syncthreads();
            for (int i = threadIdx.x; i < (TY + 2) * TX; i += NTHREADS) {
                int ry = i >> 5;
                int rx = i & (TX - 1);
                mx1[ry][rx] = fmin3(raw[ry][rx], raw[ry][rx + 1], raw[ry][rx + 2]);
            }
            __syncthreads();
            a = fmin3(mx1[ly][lx], mx1[ly + 1][lx], mx1[ly + 2][lx]);
        }
        float r0 = r1; r1 = r2; r2 = a;
        if (zi >= z0 + 1) {
            int zc = zi - 1;
            float v = fmin3(r0, r1, r2);
            if (APPLY_SIG) v = sigm(v);
            out[base + (size_t)zc * HWP + (size_t)((y0 + ly) * WW + x0 + lx)] = v;
        }
    }
}

// ---------------- 3x3x3 max-pool of e, fused with skel update, z-slab ----------------
// INIT:  skel = relu(aimg - M(e))          (SIG_A: aimg passed through sigmoid)
// else:  delta = relu(aimg - M(e)); skel += relu(delta - skel*delta)
template<bool INIT, bool SIG_A>
__global__ __launch_bounds__(NTHREADS) void maxupd_kernel(const float* __restrict__ e,
                                                          const float* __restrict__ aimg,
                                                          float* __restrict__ skel) {
    const int lx = threadIdx.x & (TX - 1);
    const int ly = threadIdx.x >> 5;
    const int x0 = blockIdx.x * TX;
    const int y0 = blockIdx.y * TY;
    const int slab = blockIdx.z % NSLAB;
    const int z0 = slab * ZS;
    const size_t base = (size_t)(blockIdx.z / NSLAB) * DHW;

    __shared__ float raw[TY + 2][TX + 2];
    __shared__ float mx1[TY + 2][TX];

    const float G = -INFINITY;
    float r1 = G, r2 = G;

    for (int zi = z0 - 1; zi <= z0 + ZS; ++zi) {
        float a = G;
        if ((unsigned)zi < DDP) {
            const float* pl = e + base + (size_t)zi * HWP;
            for (int i = threadIdx.x; i < (TY + 2) * (TX + 2); i += NTHREADS) {
                int ry = i / (TX + 2);
                int rx = i - ry * (TX + 2);
                int gy = y0 + ry - 1;
                int gx = x0 + rx - 1;
                float v = G;
                if ((unsigned)gy < HH && (unsigned)gx < WW) v = pl[gy * WW + gx];
                raw[ry][rx] = v;
            }
            __syncthreads();
            for (int i = threadIdx.x; i < (TY + 2) * TX; i += NTHREADS) {
                int ry = i >> 5;
                int rx = i & (TX - 1);
                mx1[ry][rx] = fmax3(raw[ry][rx], raw[ry][rx + 1], raw[ry][rx + 2]);
            }
            __syncthreads();
            a = fmax3(mx1[ly][lx], mx1[ly + 1][lx], mx1[ly + 2][lx]);
        }
        float r0 = r1; r1 = r2; r2 = a;
        if (zi >= z0 + 1) {
            int zc = zi - 1;
            size_t idx = base + (size_t)zc * HWP + (size_t)((y0 + ly) * WW + x0 + lx);
            float o = fmax3(r0, r1, r2);
            float av = aimg[idx];
            if (SIG_A) av = sigm(av);
            float d = fmaxf(av - o, 0.f);
            if (INIT) {
                skel[idx] = d;
            } else {
                float s = skel[idx];
                skel[idx] = s + fmaxf(d - s * d, 0.f);
            }
        }
    }
}

// ---------------- deterministic 2-sum reduction: p0 += sum(skel*f(other)), p1 += sum(skel) ----
template<bool SIG_O, bool ACCUM>
__global__ __launch_bounds__(NTHREADS) void reduce2_kernel(const float* __restrict__ skel,
                                                           const float* __restrict__ other,
                                                           float* __restrict__ p0,
                                                           float* __restrict__ p1,
                                                           int n) {
    float a0 = 0.f, a1 = 0.f;
    for (int i = blockIdx.x * NTHREADS + threadIdx.x; i < n; i += gridDim.x * NTHREADS) {
        float s = skel[i];
        float o = other[i];
        if (SIG_O) o = sigm(o);
        a0 += s * o;
        a1 += s;
    }
    for (int off = 32; off > 0; off >>= 1) {
        a0 += __shfl_down(a0, off);
        a1 += __shfl_down(a1, off);
    }
    __shared__ float red[4][2];
    int wave = threadIdx.x >> 6;
    if ((threadIdx.x & 63) == 0) { red[wave][0] = a0; red[wave][1] = a1; }
    __syncthreads();
    if (threadIdx.x == 0) {
        float s0 = 0.f, s1 = 0.f;
        for (int w = 0; w < 4; ++w) { s0 += red[w][0]; s1 += red[w][1]; }
        if (ACCUM) { p0[blockIdx.x] += s0; p1[blockIdx.x] += s1; }
        else       { p0[blockIdx.x] = s0;  p1[blockIdx.x] = s1;  }
    }
}

__global__ __launch_bounds__(NTHREADS) void finalize_kernel(const float* __restrict__ part,
                                                            float* __restrict__ out) {
    float a0 = 0.f, a1 = 0.f, a2 = 0.f, a3 = 0.f;
    for (int i = threadIdx.x; i < RED_BLOCKS; i += NTHREADS) {
        a0 += part[0 * RED_BLOCKS + i];
        a1 += part[1 * RED_BLOCKS + i];
        a2 += part[2 * RED_BLOCKS + i];
        a3 += part[3 * RED_BLOCKS + i];
    }
    for (int off = 32; off > 0; off >>= 1) {
        a0 += __shfl_down(a0, off);
        a1 += __shfl_down(a1, off);
        a2 += __shfl_down(a2, off);
        a3 += __shfl_down(a3, off);
    }
    __shared__ float red[4][4];
    int wave = threadIdx.x >> 6;
    if ((threadIdx.x & 63) == 0) {
        red[wave][0] = a0; red[wave][1] = a1; red[wave][2] = a2; red[wave][3] = a3;
    }
    __syncthreads();
    if (threadIdx.x == 0) {
        float s0 = 0.f, s1 = 0.f, s2 = 0.f, s3 = 0.f;
        for (int w = 0; w < 4; ++w) {
            s0 += red[w][0]; s1 += red[w][1]; s2 += red[w][2]; s3 += red[w][3];
        }
        float tprec = (s0 + 1.f) / (s1 + 1.f);
        float tsens = (s2 + 1.f) / (s3 + 1.f);
        float cl = 2.f * tprec * tsens / (tprec + tsens + 1.f);
        out[0] = 1.f - cl;
    }
}

__global__ void sentinel_kernel(float* out, float v) { out[0] = v; }

// Run one branch's skeletonization chain on `vols` volumes starting at `input`.
static void run_branch(const float* input, bool dosig,
                       float* A, float* B, float* SKEL,
                       int vols, hipStream_t stream) {
    dim3 grid(WW / TX, HH / TY, vols * NSLAB);
    if (dosig) erode_kernel<true ><<<grid, NTHREADS, 0, stream>>>(input, B);
    else       erode_kernel<false><<<grid, NTHREADS, 0, stream>>>(input, B);
    if (dosig) maxupd_kernel<true, true ><<<grid, NTHREADS, 0, stream>>>(B, input, SKEL);
    else       maxupd_kernel<true, false><<<grid, NTHREADS, 0, stream>>>(B, input, SKEL);
    float* cur = B;
    float* oth = A;
    for (int t = 0; t < NITER; ++t) {
        erode_kernel<false><<<grid, NTHREADS, 0, stream>>>(cur, oth);
        maxupd_kernel<false, false><<<grid, NTHREADS, 0, stream>>>(oth, cur, SKEL);
        float* tmp = cur; cur = oth; oth = tmp;
    }
}

extern "C" void kernel_launch(void* const* d_in, const int* in_sizes, int n_in,
                              void* d_out, int out_size, void* d_ws, size_t ws_size,
                              hipStream_t stream) {
    const float* ypred = (const float*)d_in[0];
    const float* ytrue = (const float*)d_in[1];
    float* out = (float*)d_out;

    const size_t partBytes = (size_t)4 * RED_BLOCKS * sizeof(float);
    const size_t need2 = (size_t)3 * N2 * sizeof(float) + partBytes;   // ~151 MB
    const size_t need1 = (size_t)3 * DHW * sizeof(float) + partBytes;  // ~75.5 MB

    if (ws_size >= need2) {
        float* A    = (float*)d_ws;
        float* B    = A + N2;
        float* SKEL = B + N2;
        float* PART = SKEL + N2;

        run_branch(ypred, true, A, B, SKEL, 2, stream);
        reduce2_kernel<false, false><<<RED_BLOCKS, NTHREADS, 0, stream>>>(
            SKEL, ytrue, PART + 0 * RED_BLOCKS, PART + 1 * RED_BLOCKS, N2);
        run_branch(ytrue, false, A, B, SKEL, 2, stream);
        reduce2_kernel<true, false><<<RED_BLOCKS, NTHREADS, 0, stream>>>(
            SKEL, ypred, PART + 2 * RED_BLOCKS, PART + 3 * RED_BLOCKS, N2);

        finalize_kernel<<<1, NTHREADS, 0, stream>>>(PART, out);
    } else if (ws_size >= need1) {
        float* A    = (float*)d_ws;
        float* B    = A + DHW;
        float* SKEL = B + DHW;
        float* PART = SKEL + DHW;

        for (int v = 0; v < 2; ++v) {
            run_branch(ypred + (size_t)v * DHW, true, A, B, SKEL, 1, stream);
            if (v == 0)
                reduce2_kernel<false, false><<<RED_BLOCKS, NTHREADS, 0, stream>>>(
                    SKEL, ytrue + (size_t)v * DHW, PART + 0 * RED_BLOCKS, PART + 1 * RED_BLOCKS, DHW);
            else
                reduce2_kernel<false, true><<<RED_BLOCKS, NTHREADS, 0, stream>>>(
                    SKEL, ytrue + (size_t)v * DHW, PART + 0 * RED_BLOCKS, PART + 1 * RED_BLOCKS, DHW);
        }
        for (int v = 0; v < 2; ++v) {
            run_branch(ytrue + (size_t)v * DHW, false, A, B, SKEL, 1, stream);
            if (v == 0)
                reduce2_kernel<true, false><<<RED_BLOCKS, NTHREADS, 0, stream>>>(
                    SKEL, ypred + (size_t)v * DHW, PART + 2 * RED_BLOCKS, PART + 3 * RED_BLOCKS, DHW);
            else
                reduce2_kernel<true, true><<<RED_BLOCKS, NTHREADS, 0, stream>>>(
                    SKEL, ypred + (size_t)v * DHW, PART + 2 * RED_BLOCKS, PART + 3 * RED_BLOCKS, DHW);
        }
        finalize_kernel<<<1, NTHREADS, 0, stream>>>(PART, out);
    } else {
        sentinel_kernel<<<1, 1, 0, stream>>>(out, -111111.f);
    }
}

// Round 4
// 4389.486 us; speedup vs baseline: 4.0544x; 1.5560x over previous
//
#include <hip/hip_runtime.h>
#include <math.h>

#define WW 256
#define HH 256
#define DDP 96
#define HWP (WW*HH)            // 65536
#define DHW (DDP*HWP)          // 6291456 per volume
#define N2 (2*DHW)
#define N4 (4*DHW)
#define TX 64
#define TY 16
#define NT 512
#define ZS 16
#define NSLAB (DDP/ZS)         // 6
#define RED_BLOCKS 1024
#define NITER 40

typedef unsigned int u32;
typedef unsigned short u16;

__device__ __forceinline__ float fmin3(float a, float b, float c) { return fminf(a, fminf(b, c)); }
__device__ __forceinline__ float fmax3(float a, float b, float c) { return fmaxf(a, fmaxf(b, c)); }
__device__ __forceinline__ float sigm(float x) { return 1.f / (1.f + expf(-x)); }

__device__ __forceinline__ float bf2f(u16 h) {
    u32 u = ((u32)h) << 16;
    return __builtin_bit_cast(float, u);
}
__device__ __forceinline__ u16 f2bf(float f) {  // round-to-nearest-even
    u32 u = __builtin_bit_cast(u32, f);
    return (u16)((u + 0x7fffu + ((u >> 16) & 1u)) >> 16);
}
__device__ __forceinline__ u32 pack2(float a, float b) {
    return (u32)f2bf(a) | ((u32)f2bf(b) << 16);
}

// LDS planes: raw [TY+2][TX+4] (cols start at x0-2, even-aligned for packed loads),
//             mx1 [TY+2][TX].
// Thread map: tx2 = t&31 (x-pair), ty = t>>5 (row). Each thread outputs x = x0+2*tx2, +1.

// ---------------- erosion: e_out = min-pool3(e_in), SAME-clamped, z-slab ----------------
// INIT: read fp32 inputs (ypred vols 0,1 / ytrue vols 2,3); sigmoid applied to pooled
// value for pred vols (monotone => commutes with min).
template<bool INIT>
__global__ __launch_bounds__(NT) void erode_kernel(const u16* __restrict__ ein,
                                                   const float* __restrict__ ypred,
                                                   const float* __restrict__ ytrue,
                                                   u16* __restrict__ eout) {
    const int tx2 = threadIdx.x & 31;
    const int ty  = threadIdx.x >> 5;
    const int x0 = blockIdx.x * TX;
    const int y0 = blockIdx.y * TY;
    const int vol = blockIdx.z / NSLAB;
    const int z0 = (blockIdx.z % NSLAB) * ZS;
    const size_t base = (size_t)vol * DHW;

    const float* fin = nullptr;
    bool dosig = false;
    if (INIT) {
        if (vol < 2) { fin = ypred + base; dosig = true; }
        else         { fin = ytrue + (size_t)(vol - 2) * DHW; }
    }

    __shared__ float raw[TY + 2][TX + 4];
    __shared__ float mx1[TY + 2][TX];

    float q0[2], q1[2], q2[2];
    q0[0]=q0[1]=q1[0]=q1[1]=q2[0]=q2[1]=INFINITY;

    for (int zi = z0 - 1; zi <= z0 + ZS; ++zi) {
        const bool zok = (unsigned)zi < DDP;
        const size_t zoff = (size_t)zi * HWP;
        for (int i = threadIdx.x; i < (TY + 2) * ((TX + 4) / 2); i += NT) {
            int ry = i / ((TX + 4) / 2);
            int rx2 = i - ry * ((TX + 4) / 2);
            int gy = y0 + ry - 1;
            int gx0 = x0 + 2 * rx2 - 2;
            float v0 = INFINITY, v1 = INFINITY;
            if (zok && (unsigned)gy < HH && (unsigned)gx0 < WW) {
                if (INIT) {
                    float2 fv = *reinterpret_cast<const float2*>(fin + zoff + (size_t)gy * WW + gx0);
                    v0 = fv.x; v1 = fv.y;
                } else {
                    u32 p = *reinterpret_cast<const u32*>(ein + base + zoff + (size_t)gy * WW + gx0);
                    v0 = bf2f((u16)p); v1 = bf2f((u16)(p >> 16));
                }
            }
            *reinterpret_cast<float2*>(&raw[ry][2 * rx2]) = make_float2(v0, v1);
        }
        __syncthreads();
        for (int i = threadIdx.x; i < (TY + 2) * TX; i += NT) {
            int ry = i >> 6;
            int rx = i & (TX - 1);
            mx1[ry][rx] = fmin3(raw[ry][rx + 1], raw[ry][rx + 2], raw[ry][rx + 3]);
        }
        __syncthreads();
        float2 m0 = *reinterpret_cast<float2*>(&mx1[ty][2 * tx2]);
        float2 m1 = *reinterpret_cast<float2*>(&mx1[ty + 1][2 * tx2]);
        float2 m2 = *reinterpret_cast<float2*>(&mx1[ty + 2][2 * tx2]);
        float a0 = fmin3(m0.x, m1.x, m2.x);
        float a1 = fmin3(m0.y, m1.y, m2.y);
        q0[0]=q1[0]; q1[0]=q2[0]; q2[0]=a0;
        q0[1]=q1[1]; q1[1]=q2[1]; q2[1]=a1;
        if (zi >= z0 + 1) {
            int zc = zi - 1;
            float v0 = fmin3(q0[0], q1[0], q2[0]);
            float v1 = fmin3(q0[1], q1[1], q2[1]);
            if (INIT && dosig) { v0 = sigm(v0); v1 = sigm(v1); }
            size_t idx = base + (size_t)zc * HWP + (size_t)(y0 + ty) * WW + x0 + 2 * tx2;
            *reinterpret_cast<u32*>(eout + idx) = pack2(v0, v1);
        }
    }
}

// ---------------- max-pool3(e) fused with skel update, z-slab ----------------
// INIT:  skel = relu(aimg - M(e)), aimg = sigmoid(ypred) / ytrue from fp32 inputs
// else:  delta = relu(aimg - M(e)); skel += relu(delta - skel*delta); aimg = bf16 buffer
template<bool INIT>
__global__ __launch_bounds__(NT) void maxupd_kernel(const u16* __restrict__ e,
                                                    const u16* __restrict__ aimg,
                                                    const float* __restrict__ ypred,
                                                    const float* __restrict__ ytrue,
                                                    u16* __restrict__ skel) {
    const int tx2 = threadIdx.x & 31;
    const int ty  = threadIdx.x >> 5;
    const int x0 = blockIdx.x * TX;
    const int y0 = blockIdx.y * TY;
    const int vol = blockIdx.z / NSLAB;
    const int z0 = (blockIdx.z % NSLAB) * ZS;
    const size_t base = (size_t)vol * DHW;

    const float* fin = nullptr;
    bool dosig = false;
    if (INIT) {
        if (vol < 2) { fin = ypred + base; dosig = true; }
        else         { fin = ytrue + (size_t)(vol - 2) * DHW; }
    }

    __shared__ float raw[TY + 2][TX + 4];
    __shared__ float mx1[TY + 2][TX];

    float q0[2], q1[2], q2[2];
    q0[0]=q0[1]=q1[0]=q1[1]=q2[0]=q2[1]=-INFINITY;

    for (int zi = z0 - 1; zi <= z0 + ZS; ++zi) {
        const bool zok = (unsigned)zi < DDP;
        const size_t zoff = (size_t)zi * HWP;
        for (int i = threadIdx.x; i < (TY + 2) * ((TX + 4) / 2); i += NT) {
            int ry = i / ((TX + 4) / 2);
            int rx2 = i - ry * ((TX + 4) / 2);
            int gy = y0 + ry - 1;
            int gx0 = x0 + 2 * rx2 - 2;
            float v0 = -INFINITY, v1 = -INFINITY;
            if (zok && (unsigned)gy < HH && (unsigned)gx0 < WW) {
                u32 p = *reinterpret_cast<const u32*>(e + base + zoff + (size_t)gy * WW + gx0);
                v0 = bf2f((u16)p); v1 = bf2f((u16)(p >> 16));
            }
            *reinterpret_cast<float2*>(&raw[ry][2 * rx2]) = make_float2(v0, v1);
        }
        __syncthreads();
        for (int i = threadIdx.x; i < (TY + 2) * TX; i += NT) {
            int ry = i >> 6;
            int rx = i & (TX - 1);
            mx1[ry][rx] = fmax3(raw[ry][rx + 1], raw[ry][rx + 2], raw[ry][rx + 3]);
        }
        __syncthreads();
        float2 m0 = *reinterpret_cast<float2*>(&mx1[ty][2 * tx2]);
        float2 m1 = *reinterpret_cast<float2*>(&mx1[ty + 1][2 * tx2]);
        float2 m2 = *reinterpret_cast<float2*>(&mx1[ty + 2][2 * tx2]);
        float a0 = fmax3(m0.x, m1.x, m2.x);
        float a1 = fmax3(m0.y, m1.y, m2.y);
        q0[0]=q1[0]; q1[0]=q2[0]; q2[0]=a0;
        q0[1]=q1[1]; q1[1]=q2[1]; q2[1]=a1;
        if (zi >= z0 + 1) {
            int zc = zi - 1;
            size_t voff = (size_t)zc * HWP + (size_t)(y0 + ty) * WW + x0 + 2 * tx2;
            size_t idx = base + voff;
            float o0 = fmax3(q0[0], q1[0], q2[0]);
            float o1 = fmax3(q0[1], q1[1], q2[1]);
            float av0, av1;
            if (INIT) {
                float2 fv = *reinterpret_cast<const float2*>(fin + voff);
                av0 = fv.x; av1 = fv.y;
                if (dosig) { av0 = sigm(av0); av1 = sigm(av1); }
            } else {
                u32 ap = *reinterpret_cast<const u32*>(aimg + idx);
                av0 = bf2f((u16)ap); av1 = bf2f((u16)(ap >> 16));
            }
            float d0 = fmaxf(av0 - o0, 0.f);
            float d1 = fmaxf(av1 - o1, 0.f);
            u32 pk;
            if (INIT) {
                pk = pack2(d0, d1);
            } else {
                u32 sp = *reinterpret_cast<const u32*>(skel + idx);
                float s0 = bf2f((u16)sp), s1 = bf2f((u16)(sp >> 16));
                s0 += fmaxf(d0 - s0 * d0, 0.f);
                s1 += fmaxf(d1 - s1 * d1, 0.f);
                pk = pack2(s0, s1);
            }
            *reinterpret_cast<u32*>(skel + idx) = pk;
        }
    }
}

// ---------------- deterministic 4-sum reduction ----------------
__global__ __launch_bounds__(256) void reduce4_kernel(const u16* __restrict__ skel,
                                                      const float* __restrict__ ytrue,
                                                      const float* __restrict__ ypred,
                                                      float* __restrict__ part) {
    const u32* sp = (const u32*)skel;            // skel_pred (vols 0,1)
    const u32* st = (const u32*)(skel + N2);     // skel_true (vols 2,3)
    const float2* yt = (const float2*)ytrue;
    const float2* yp = (const float2*)ypred;
    float a0 = 0.f, a1 = 0.f, a2 = 0.f, a3 = 0.f;
    for (int i = blockIdx.x * 256 + threadIdx.x; i < N2 / 2; i += gridDim.x * 256) {
        u32 a = sp[i];
        u32 b = st[i];
        float2 t = yt[i];
        float2 q = yp[i];
        float s0 = bf2f((u16)a), s1 = bf2f((u16)(a >> 16));
        float u0 = bf2f((u16)b), u1 = bf2f((u16)(b >> 16));
        a0 += s0 * t.x + s1 * t.y;
        a1 += s0 + s1;
        a2 += u0 * sigm(q.x) + u1 * sigm(q.y);
        a3 += u0 + u1;
    }
    for (int off = 32; off > 0; off >>= 1) {
        a0 += __shfl_down(a0, off);
        a1 += __shfl_down(a1, off);
        a2 += __shfl_down(a2, off);
        a3 += __shfl_down(a3, off);
    }
    __shared__ float red[4][4];
    int wave = threadIdx.x >> 6;
    if ((threadIdx.x & 63) == 0) {
        red[wave][0] = a0; red[wave][1] = a1; red[wave][2] = a2; red[wave][3] = a3;
    }
    __syncthreads();
    if (threadIdx.x == 0) {
        float s0 = 0.f, s1 = 0.f, s2 = 0.f, s3 = 0.f;
        for (int w = 0; w < 4; ++w) {
            s0 += red[w][0]; s1 += red[w][1]; s2 += red[w][2]; s3 += red[w][3];
        }
        part[0 * RED_BLOCKS + blockIdx.x] = s0;
        part[1 * RED_BLOCKS + blockIdx.x] = s1;
        part[2 * RED_BLOCKS + blockIdx.x] = s2;
        part[3 * RED_BLOCKS + blockIdx.x] = s3;
    }
}

__global__ __launch_bounds__(256) void finalize_kernel(const float* __restrict__ part,
                                                       float* __restrict__ out) {
    float a0 = 0.f, a1 = 0.f, a2 = 0.f, a3 = 0.f;
    for (int i = threadIdx.x; i < RED_BLOCKS; i += 256) {
        a0 += part[0 * RED_BLOCKS + i];
        a1 += part[1 * RED_BLOCKS + i];
        a2 += part[2 * RED_BLOCKS + i];
        a3 += part[3 * RED_BLOCKS + i];
    }
    for (int off = 32; off > 0; off >>= 1) {
        a0 += __shfl_down(a0, off);
        a1 += __shfl_down(a1, off);
        a2 += __shfl_down(a2, off);
        a3 += __shfl_down(a3, off);
    }
    __shared__ float red[4][4];
    int wave = threadIdx.x >> 6;
    if ((threadIdx.x & 63) == 0) {
        red[wave][0] = a0; red[wave][1] = a1; red[wave][2] = a2; red[wave][3] = a3;
    }
    __syncthreads();
    if (threadIdx.x == 0) {
        float s0 = 0.f, s1 = 0.f, s2 = 0.f, s3 = 0.f;
        for (int w = 0; w < 4; ++w) {
            s0 += red[w][0]; s1 += red[w][1]; s2 += red[w][2]; s3 += red[w][3];
        }
        float tprec = (s0 + 1.f) / (s1 + 1.f);
        float tsens = (s2 + 1.f) / (s3 + 1.f);
        float cl = 2.f * tprec * tsens / (tprec + tsens + 1.f);
        out[0] = 1.f - cl;
    }
}

__global__ void sentinel_kernel(float* out, float v) { out[0] = v; }

extern "C" void kernel_launch(void* const* d_in, const int* in_sizes, int n_in,
                              void* d_out, int out_size, void* d_ws, size_t ws_size,
                              hipStream_t stream) {
    const float* ypred = (const float*)d_in[0];
    const float* ytrue = (const float*)d_in[1];
    float* out = (float*)d_out;

    // 3 bf16 buffers of N4 + fp32 partials == exactly the budget proven in rounds 2-3.
    const size_t need = (size_t)3 * N4 * sizeof(u16) + (size_t)4 * RED_BLOCKS * sizeof(float);
    if (ws_size < need) {
        sentinel_kernel<<<1, 1, 0, stream>>>(out, -111111.f);
        return;
    }

    u16* A    = (u16*)d_ws;
    u16* B    = A + N4;
    u16* SKEL = B + N4;
    float* PART = (float*)(SKEL + N4);

    dim3 grid(WW / TX, HH / TY, 4 * NSLAB);   // 4 x 16 x 24 = 1536 blocks

    // e_1 = E(e_0), with sigmoid fused for pred volumes
    erode_kernel<true><<<grid, NT, 0, stream>>>(nullptr, ypred, ytrue, B);
    // skel = relu(e_0 - M(e_1))
    maxupd_kernel<true><<<grid, NT, 0, stream>>>(B, nullptr, ypred, ytrue, SKEL);

    u16* cur = B;   // e_t
    u16* oth = A;
    for (int t = 1; t <= NITER; ++t) {
        erode_kernel<false><<<grid, NT, 0, stream>>>(cur, nullptr, nullptr, oth);   // e_{t+1}
        maxupd_kernel<false><<<grid, NT, 0, stream>>>(oth, cur, nullptr, nullptr, SKEL);
        u16* tmp = cur; cur = oth; oth = tmp;
    }

    reduce4_kernel<<<RED_BLOCKS, 256, 0, stream>>>(SKEL, ytrue, ypred, PART);
    finalize_kernel<<<1, 256, 0, stream>>>(PART, out);
}

// Round 5
// 2934.623 us; speedup vs baseline: 6.0645x; 1.4958x over previous
//
#include <hip/hip_runtime.h>
#include <math.h>

#define WW 256
#define HH 256
#define DDP 96
#define HWP (WW*HH)            // 65536
#define DHW (DDP*HWP)          // 6291456 per volume
#define N2 (2*DHW)
#define N4 (4*DHW)
#define TX 64                  // x extent per block (32 threads x 2 px)
#define TY 8                   // y rows per block
#define NT 256
#define ZS 12
#define NSLAB (DDP/ZS)         // 8
#define RED_BLOCKS 1024
#define NITER 40

typedef unsigned int u32;
typedef unsigned short u16;

__device__ __forceinline__ float fmin3(float a, float b, float c) { return fminf(a, fminf(b, c)); }
__device__ __forceinline__ float fmax3(float a, float b, float c) { return fmaxf(a, fmaxf(b, c)); }
__device__ __forceinline__ float sigm(float x) { return 1.f / (1.f + expf(-x)); }

__device__ __forceinline__ float bf2f(u16 h) {
    u32 u = ((u32)h) << 16;
    return __builtin_bit_cast(float, u);
}
__device__ __forceinline__ u16 f2bf(float f) {  // round-to-nearest-even
    u32 u = __builtin_bit_cast(u32, f);
    return (u16)((u + 0x7fffu + ((u >> 16) & 1u)) >> 16);
}
__device__ __forceinline__ u32 pack2(float a, float b) {
    return (u32)f2bf(a) | ((u32)f2bf(b) << 16);
}

// Replicate-clamp loads: for 3-wide clamped windows, clamping coordinates to the
// volume replicates an element already inside window-intersect-volume, so min AND
// max pooling both stay exact. One raw plane serves both.

// ---------------- init erosion: EB = E(f(input)), f = sigmoid for vols 0,1 ----------------
__global__ __launch_bounds__(NT) void erode_init_kernel(const float* __restrict__ ypred,
                                                        const float* __restrict__ ytrue,
                                                        u16* __restrict__ eout) {
    const int tx2 = threadIdx.x & 31;
    const int ty  = threadIdx.x >> 5;
    const int x0 = blockIdx.x * TX;
    const int y0 = blockIdx.y * TY;
    const int vol = blockIdx.z / NSLAB;
    const int z0 = (blockIdx.z % NSLAB) * ZS;
    const size_t base = (size_t)vol * DHW;
    const float* fin = (vol < 2) ? (ypred + base) : (ytrue + (size_t)(vol - 2) * DHW);
    const bool dosig = (vol < 2);

    __shared__ float raw[TY + 2][TX + 4];
    __shared__ float mnx[TY + 2][TX];

    float q0[2], q1[2], q2[2];
    q0[0]=q0[1]=q1[0]=q1[1]=q2[0]=q2[1]=INFINITY;

    for (int zi = z0 - 1; zi <= z0 + ZS; ++zi) {
        const int zl = min(max(zi, 0), DDP - 1);
        const float* pl = fin + (size_t)zl * HWP;
        for (int i = threadIdx.x; i < (TY + 2) * ((TX + 4) / 2); i += NT) {
            int ry = i / ((TX + 4) / 2);
            int rx2 = i - ry * ((TX + 4) / 2);
            int gy = y0 + ry - 1; gy = min(max(gy, 0), HH - 1);
            int gx0 = x0 + 2 * rx2 - 2;
            float v0, v1;
            if (gx0 < 0)        { float t = pl[(size_t)gy * WW];          v0 = v1 = t; }
            else if (gx0 >= WW) { float t = pl[(size_t)gy * WW + WW - 1]; v0 = v1 = t; }
            else {
                float2 fv = *reinterpret_cast<const float2*>(pl + (size_t)gy * WW + gx0);
                v0 = fv.x; v1 = fv.y;
            }
            *reinterpret_cast<float2*>(&raw[ry][2 * rx2]) = make_float2(v0, v1);
        }
        __syncthreads();
        for (int i = threadIdx.x; i < (TY + 2) * TX; i += NT) {
            int ry = i >> 6;
            int rx = i & (TX - 1);
            mnx[ry][rx] = fmin3(raw[ry][rx + 1], raw[ry][rx + 2], raw[ry][rx + 3]);
        }
        __syncthreads();
        float2 m0 = *reinterpret_cast<float2*>(&mnx[ty][2 * tx2]);
        float2 m1 = *reinterpret_cast<float2*>(&mnx[ty + 1][2 * tx2]);
        float2 m2 = *reinterpret_cast<float2*>(&mnx[ty + 2][2 * tx2]);
        q0[0]=q1[0]; q1[0]=q2[0]; q2[0]=fmin3(m0.x, m1.x, m2.x);
        q0[1]=q1[1]; q1[1]=q2[1]; q2[1]=fmin3(m0.y, m1.y, m2.y);
        if (zi >= z0 + 1) {
            int zc = zi - 1;
            float v0 = fmin3(q0[0], q1[0], q2[0]);
            float v1 = fmin3(q0[1], q1[1], q2[1]);
            if (dosig) { v0 = sigm(v0); v1 = sigm(v1); }
            size_t idx = base + (size_t)zc * HWP + (size_t)(y0 + ty) * WW + x0 + 2 * tx2;
            *reinterpret_cast<u32*>(eout + idx) = pack2(v0, v1);
        }
    }
}

// ---------------- fused: skel update for iter t AND e_{t+2} = E(e_{t+1}) ----------------
// halo buffer = e_{t+1} (read with +-1 halo; both M and E pooled from it).
// eaw = e_t: read pointwise as aimg (INIT: aimg from fp32 inputs instead),
//            overwritten in-place with e_{t+2} (same idx, same thread -> safe).
// INIT:  skel = relu(aimg - M);   else: d = relu(aimg - M); skel += relu(d - skel*d)
template<bool INIT, bool WRITE_E>
__global__ __launch_bounds__(NT) void fused_kernel(const u16* __restrict__ ehalo,
                                                   u16* __restrict__ eaw,
                                                   const float* __restrict__ ypred,
                                                   const float* __restrict__ ytrue,
                                                   u16* __restrict__ skel) {
    const int tx2 = threadIdx.x & 31;
    const int ty  = threadIdx.x >> 5;
    const int x0 = blockIdx.x * TX;
    const int y0 = blockIdx.y * TY;
    const int vol = blockIdx.z / NSLAB;
    const int z0 = (blockIdx.z % NSLAB) * ZS;
    const size_t base = (size_t)vol * DHW;

    const float* fin = nullptr;
    bool dosig = false;
    if (INIT) {
        if (vol < 2) { fin = ypred + base; dosig = true; }
        else         { fin = ytrue + (size_t)(vol - 2) * DHW; }
    }

    __shared__ float raw[TY + 2][TX + 4];
    __shared__ float mnx[TY + 2][TX];
    __shared__ float mxx[TY + 2][TX];

    float n0[2], n1[2], n2[2];   // erosion ring (min)
    float m0[2], m1[2], m2[2];   // dilation ring (max)
    n0[0]=n0[1]=n1[0]=n1[1]=n2[0]=n2[1]=INFINITY;
    m0[0]=m0[1]=m1[0]=m1[1]=m2[0]=m2[1]=-INFINITY;

    for (int zi = z0 - 1; zi <= z0 + ZS; ++zi) {
        const int zl = min(max(zi, 0), DDP - 1);
        const u16* pl = ehalo + base + (size_t)zl * HWP;
        for (int i = threadIdx.x; i < (TY + 2) * ((TX + 4) / 2); i += NT) {
            int ry = i / ((TX + 4) / 2);
            int rx2 = i - ry * ((TX + 4) / 2);
            int gy = y0 + ry - 1; gy = min(max(gy, 0), HH - 1);
            int gx0 = x0 + 2 * rx2 - 2;
            float v0, v1;
            if (gx0 < 0)        { float t = bf2f(pl[(size_t)gy * WW]);          v0 = v1 = t; }
            else if (gx0 >= WW) { float t = bf2f(pl[(size_t)gy * WW + WW - 1]); v0 = v1 = t; }
            else {
                u32 p = *reinterpret_cast<const u32*>(pl + (size_t)gy * WW + gx0);
                v0 = bf2f((u16)p); v1 = bf2f((u16)(p >> 16));
            }
            *reinterpret_cast<float2*>(&raw[ry][2 * rx2]) = make_float2(v0, v1);
        }
        __syncthreads();
        for (int i = threadIdx.x; i < (TY + 2) * TX; i += NT) {
            int ry = i >> 6;
            int rx = i & (TX - 1);
            float a = raw[ry][rx + 1], b = raw[ry][rx + 2], c = raw[ry][rx + 3];
            mnx[ry][rx] = fmin3(a, b, c);
            mxx[ry][rx] = fmax3(a, b, c);
        }
        __syncthreads();
        float2 a0 = *reinterpret_cast<float2*>(&mnx[ty][2 * tx2]);
        float2 a1 = *reinterpret_cast<float2*>(&mnx[ty + 1][2 * tx2]);
        float2 a2 = *reinterpret_cast<float2*>(&mnx[ty + 2][2 * tx2]);
        float2 b0 = *reinterpret_cast<float2*>(&mxx[ty][2 * tx2]);
        float2 b1 = *reinterpret_cast<float2*>(&mxx[ty + 1][2 * tx2]);
        float2 b2 = *reinterpret_cast<float2*>(&mxx[ty + 2][2 * tx2]);
        n0[0]=n1[0]; n1[0]=n2[0]; n2[0]=fmin3(a0.x, a1.x, a2.x);
        n0[1]=n1[1]; n1[1]=n2[1]; n2[1]=fmin3(a0.y, a1.y, a2.y);
        m0[0]=m1[0]; m1[0]=m2[0]; m2[0]=fmax3(b0.x, b1.x, b2.x);
        m0[1]=m1[1]; m1[1]=m2[1]; m2[1]=fmax3(b0.y, b1.y, b2.y);
        if (zi >= z0 + 1) {
            int zc = zi - 1;
            size_t voff = (size_t)zc * HWP + (size_t)(y0 + ty) * WW + x0 + 2 * tx2;
            size_t idx = base + voff;
            float o0 = fmax3(m0[0], m1[0], m2[0]);
            float o1 = fmax3(m0[1], m1[1], m2[1]);
            float av0, av1;
            if (INIT) {
                float2 fv = *reinterpret_cast<const float2*>(fin + voff);
                av0 = fv.x; av1 = fv.y;
                if (dosig) { av0 = sigm(av0); av1 = sigm(av1); }
            } else {
                u32 ap = *reinterpret_cast<const u32*>(eaw + idx);
                av0 = bf2f((u16)ap); av1 = bf2f((u16)(ap >> 16));
            }
            float d0 = fmaxf(av0 - o0, 0.f);
            float d1 = fmaxf(av1 - o1, 0.f);
            u32 pk;
            if (INIT) {
                pk = pack2(d0, d1);
            } else {
                u32 sp = *reinterpret_cast<const u32*>(skel + idx);
                float s0 = bf2f((u16)sp), s1 = bf2f((u16)(sp >> 16));
                s0 += fmaxf(d0 - s0 * d0, 0.f);
                s1 += fmaxf(d1 - s1 * d1, 0.f);
                pk = pack2(s0, s1);
            }
            *reinterpret_cast<u32*>(skel + idx) = pk;
            if (WRITE_E) {
                *reinterpret_cast<u32*>(eaw + idx) = pack2(fmin3(n0[0], n1[0], n2[0]),
                                                           fmin3(n0[1], n1[1], n2[1]));
            }
        }
    }
}

// ---------------- deterministic 4-sum reduction ----------------
__global__ __launch_bounds__(256) void reduce4_kernel(const u16* __restrict__ skel,
                                                      const float* __restrict__ ytrue,
                                                      const float* __restrict__ ypred,
                                                      float* __restrict__ part) {
    const u32* sp = (const u32*)skel;            // skel_pred (vols 0,1)
    const u32* st = (const u32*)(skel + N2);     // skel_true (vols 2,3)
    const float2* yt = (const float2*)ytrue;
    const float2* yp = (const float2*)ypred;
    float a0 = 0.f, a1 = 0.f, a2 = 0.f, a3 = 0.f;
    for (int i = blockIdx.x * 256 + threadIdx.x; i < N2 / 2; i += gridDim.x * 256) {
        u32 a = sp[i];
        u32 b = st[i];
        float2 t = yt[i];
        float2 q = yp[i];
        float s0 = bf2f((u16)a), s1 = bf2f((u16)(a >> 16));
        float u0 = bf2f((u16)b), u1 = bf2f((u16)(b >> 16));
        a0 += s0 * t.x + s1 * t.y;
        a1 += s0 + s1;
        a2 += u0 * sigm(q.x) + u1 * sigm(q.y);
        a3 += u0 + u1;
    }
    for (int off = 32; off > 0; off >>= 1) {
        a0 += __shfl_down(a0, off);
        a1 += __shfl_down(a1, off);
        a2 += __shfl_down(a2, off);
        a3 += __shfl_down(a3, off);
    }
    __shared__ float red[4][4];
    int wave = threadIdx.x >> 6;
    if ((threadIdx.x & 63) == 0) {
        red[wave][0] = a0; red[wave][1] = a1; red[wave][2] = a2; red[wave][3] = a3;
    }
    __syncthreads();
    if (threadIdx.x == 0) {
        float s0 = 0.f, s1 = 0.f, s2 = 0.f, s3 = 0.f;
        for (int w = 0; w < 4; ++w) {
            s0 += red[w][0]; s1 += red[w][1]; s2 += red[w][2]; s3 += red[w][3];
        }
        part[0 * RED_BLOCKS + blockIdx.x] = s0;
        part[1 * RED_BLOCKS + blockIdx.x] = s1;
        part[2 * RED_BLOCKS + blockIdx.x] = s2;
        part[3 * RED_BLOCKS + blockIdx.x] = s3;
    }
}

__global__ __launch_bounds__(256) void finalize_kernel(const float* __restrict__ part,
                                                       float* __restrict__ out) {
    float a0 = 0.f, a1 = 0.f, a2 = 0.f, a3 = 0.f;
    for (int i = threadIdx.x; i < RED_BLOCKS; i += 256) {
        a0 += part[0 * RED_BLOCKS + i];
        a1 += part[1 * RED_BLOCKS + i];
        a2 += part[2 * RED_BLOCKS + i];
        a3 += part[3 * RED_BLOCKS + i];
    }
    for (int off = 32; off > 0; off >>= 1) {
        a0 += __shfl_down(a0, off);
        a1 += __shfl_down(a1, off);
        a2 += __shfl_down(a2, off);
        a3 += __shfl_down(a3, off);
    }
    __shared__ float red[4][4];
    int wave = threadIdx.x >> 6;
    if ((threadIdx.x & 63) == 0) {
        red[wave][0] = a0; red[wave][1] = a1; red[wave][2] = a2; red[wave][3] = a3;
    }
    __syncthreads();
    if (threadIdx.x == 0) {
        float s0 = 0.f, s1 = 0.f, s2 = 0.f, s3 = 0.f;
        for (int w = 0; w < 4; ++w) {
            s0 += red[w][0]; s1 += red[w][1]; s2 += red[w][2]; s3 += red[w][3];
        }
        float tprec = (s0 + 1.f) / (s1 + 1.f);
        float tsens = (s2 + 1.f) / (s3 + 1.f);
        float cl = 2.f * tprec * tsens / (tprec + tsens + 1.f);
        out[0] = 1.f - cl;
    }
}

__global__ void sentinel_kernel(float* out, float v) { out[0] = v; }

extern "C" void kernel_launch(void* const* d_in, const int* in_sizes, int n_in,
                              void* d_out, int out_size, void* d_ws, size_t ws_size,
                              hipStream_t stream) {
    const float* ypred = (const float*)d_in[0];
    const float* ytrue = (const float*)d_in[1];
    float* out = (float*)d_out;

    const size_t need = (size_t)3 * N4 * sizeof(u16) + (size_t)4 * RED_BLOCKS * sizeof(float);
    if (ws_size < need) {
        sentinel_kernel<<<1, 1, 0, stream>>>(out, -111111.f);
        return;
    }

    u16* EA   = (u16*)d_ws;
    u16* EB   = EA + N4;
    u16* SKEL = EB + N4;
    float* PART = (float*)(SKEL + N4);

    dim3 grid(WW / TX, HH / TY, 4 * NSLAB);   // 4 x 32 x 32 = 4096 blocks

    // EB = e_1 = E(f(input))
    erode_init_kernel<<<grid, NT, 0, stream>>>(ypred, ytrue, EB);
    // skel = relu(e_0 - M(e_1));  EA <- e_2 = E(e_1)
    fused_kernel<true, true><<<grid, NT, 0, stream>>>(EB, EA, ypred, ytrue, SKEL);

    // ping-pong: halo = e_{t+1}, aimg/write = e_t -> e_{t+2}
    u16* h = EA;   // e_2
    u16* a = EB;   // e_1
    for (int t = 1; t <= NITER; ++t) {
        if (t < NITER) fused_kernel<false, true ><<<grid, NT, 0, stream>>>(h, a, nullptr, nullptr, SKEL);
        else           fused_kernel<false, false><<<grid, NT, 0, stream>>>(h, a, nullptr, nullptr, SKEL);
        u16* tmp = h; h = a; a = tmp;
    }

    reduce4_kernel<<<RED_BLOCKS, 256, 0, stream>>>(SKEL, ytrue, ypred, PART);
    finalize_kernel<<<1, 256, 0, stream>>>(PART, out);
}